// Round 10
// baseline (128.648 us; speedup 1.0000x reference)
//
#include <hip/hip_runtime.h>
#include <hip/hip_bf16.h>

#define NROWS 2048

typedef __attribute__((ext_vector_type(4))) float f32x4;
typedef _Float16 f16x2 __attribute__((ext_vector_type(2)));
typedef _Float16 f16x8 __attribute__((ext_vector_type(8)));
typedef __fp16 fp16x2_raw __attribute__((ext_vector_type(2)));

union H8 { f16x8 v; f16x2 h2[4]; };

static __device__ __forceinline__ f32x4 vmax0(f32x4 a) {
    return __builtin_elementwise_max(a, (f32x4)0.f);
}
static __device__ __forceinline__ f16x8 hmax0(f16x8 a) {
    return __builtin_elementwise_max(a, (f16x8)(_Float16)0.f);
}
// v_cvt_pkrtz_f16_f32: returns __fp16x2; bit-cast to our _Float16x2
static __device__ __forceinline__ f16x2 pkrtz(float a, float b) {
    union { fp16x2_raw r; f16x2 f; } c;
    c.r = __builtin_amdgcn_cvt_pkrtz(a, b);
    return c.f;
}

// Workspace layout (float units):
//   TI   : ws[0    .. 2688)   42 x 64 (i-side: subj 0-15, rel 16-24, obj 25-40, const 41)
//   TJ   : ws[2688 .. 5376)   42 x 64 (j-side)
//   hi16 : ws[5376 .. )       2048 x 64 _Float16  (65536 B)
//   hj16 : after hi16         2048 x 64 _Float16
#define TJ_OFF   2688
#define H16_OFF  5376

// ---------------- Kernel T: fused e-table + H-table ----------------
__global__ __launch_bounds__(256) void tab_kernel(
    const float* __restrict__ subj_table, const float* __restrict__ rel_table,
    const float* __restrict__ obj_table,
    const float* __restrict__ proj_w, const float* __restrict__ proj_b,
    const float* __restrict__ w1, const float* __restrict__ b1,
    float* __restrict__ ws)
{
    __shared__ float et[64];
    const int b = blockIdx.x;            // 0..83
    const int side = b & 1;
    const int r = b >> 1;                // 0..41
    const int tid = threadIdx.x;
    const int lane = tid & 63;
    const int w = tid >> 6;

    // ---- stage 1: ET row r ----
    if (r == 41) {
        if (tid < 64) et[tid] = proj_b[tid];
    } else {
        const float* src; int off;
        if (r < 16)      { src = subj_table + r * 64;        off = 0;   }
        else if (r < 25) { src = rel_table + (r - 16) * 64;  off = 64;  }
        else             { src = obj_table + (r - 25) * 64;  off = 128; }
        const float sv = src[lane];
        #pragma unroll
        for (int t = 0; t < 4; ++t) {
            const int d0 = w * 16 + t * 4;
            float p0 = sv * proj_w[(d0 + 0) * 192 + off + lane];
            float p1 = sv * proj_w[(d0 + 1) * 192 + off + lane];
            float p2 = sv * proj_w[(d0 + 2) * 192 + off + lane];
            float p3 = sv * proj_w[(d0 + 3) * 192 + off + lane];
            #pragma unroll
            for (int m = 1; m < 64; m <<= 1) {
                p0 += __shfl_xor(p0, m, 64);
                p1 += __shfl_xor(p1, m, 64);
                p2 += __shfl_xor(p2, m, 64);
                p3 += __shfl_xor(p3, m, 64);
            }
            if (lane == 0) {
                et[d0 + 0] = p0; et[d0 + 1] = p1;
                et[d0 + 2] = p2; et[d0 + 3] = p3;
            }
        }
    }
    __syncthreads();

    // ---- stage 2: H row ----
    float* dst = ws + (side ? TJ_OFF : 0);
    const float sv2 = et[lane];
    const int woff = side * 64;
    #pragma unroll
    for (int t = 0; t < 4; ++t) {
        const int d0 = w * 16 + t * 4;
        float p0 = sv2 * w1[(d0 + 0) * 128 + woff + lane];
        float p1 = sv2 * w1[(d0 + 1) * 128 + woff + lane];
        float p2 = sv2 * w1[(d0 + 2) * 128 + woff + lane];
        float p3 = sv2 * w1[(d0 + 3) * 128 + woff + lane];
        #pragma unroll
        for (int m = 1; m < 64; m <<= 1) {
            p0 += __shfl_xor(p0, m, 64);
            p1 += __shfl_xor(p1, m, 64);
            p2 += __shfl_xor(p2, m, 64);
            p3 += __shfl_xor(p3, m, 64);
        }
        if (lane == 0) {
            const bool cst = (side == 0) && (r == 41);
            dst[r * 64 + d0 + 0] = p0 + (cst ? b1[d0 + 0] : 0.f);
            dst[r * 64 + d0 + 1] = p1 + (cst ? b1[d0 + 1] : 0.f);
            dst[r * 64 + d0 + 2] = p2 + (cst ? b1[d0 + 2] : 0.f);
            dst[r * 64 + d0 + 3] = p3 + (cst ? b1[d0 + 3] : 0.f);
        }
    }
}

// ---------------- Kernel G: gather hi/hj rows -> fp16 tables ----------------
// Row n: hi16[n] = fp16(TI[s]+TI[16+r]+TI[25+o]+TI[41]), same for hj16 with TJ.
// Identical arithmetic to the old in-block gather (absmax-invariant).
__global__ __launch_bounds__(256) void hgather_kernel(
    const int* __restrict__ subj_idx, const int* __restrict__ rel_idx,
    const int* __restrict__ obj_idx, float* __restrict__ ws)
{
    _Float16* hi16 = (_Float16*)(ws + H16_OFF);
    _Float16* hj16 = hi16 + NROWS * 64;
    const float* TI = ws;
    const float* TJ = ws + TJ_OFF;

    const int t = threadIdx.x;
    const int n = blockIdx.x * 32 + (t >> 3);
    const int c = (t & 7) * 8;

    const int s = subj_idx[n];
    const int r = 16 + rel_idx[n];
    const int o = 25 + obj_idx[n];

    const f32x4 v0 = *(const f32x4*)(TI + s * 64 + c)
                   + *(const f32x4*)(TI + r * 64 + c)
                   + *(const f32x4*)(TI + o * 64 + c)
                   + *(const f32x4*)(TI + 41 * 64 + c);
    const f32x4 v1 = *(const f32x4*)(TI + s * 64 + c + 4)
                   + *(const f32x4*)(TI + r * 64 + c + 4)
                   + *(const f32x4*)(TI + o * 64 + c + 4)
                   + *(const f32x4*)(TI + 41 * 64 + c + 4);
    H8 hp;
    hp.h2[0] = pkrtz(v0[0], v0[1]); hp.h2[1] = pkrtz(v0[2], v0[3]);
    hp.h2[2] = pkrtz(v1[0], v1[1]); hp.h2[3] = pkrtz(v1[2], v1[3]);
    *(f16x8*)&hi16[(size_t)n * 64 + c] = hp.v;

    const f32x4 u0 = *(const f32x4*)(TJ + s * 64 + c)
                   + *(const f32x4*)(TJ + r * 64 + c)
                   + *(const f32x4*)(TJ + o * 64 + c)
                   + *(const f32x4*)(TJ + 41 * 64 + c);
    const f32x4 u1 = *(const f32x4*)(TJ + s * 64 + c + 4)
                   + *(const f32x4*)(TJ + r * 64 + c + 4)
                   + *(const f32x4*)(TJ + o * 64 + c + 4)
                   + *(const f32x4*)(TJ + 41 * 64 + c + 4);
    H8 hq;
    hq.h2[0] = pkrtz(u0[0], u0[1]); hq.h2[1] = pkrtz(u0[2], u0[3]);
    hq.h2[2] = pkrtz(u1[0], u1[1]); hq.h2[3] = pkrtz(u1[2], u1[3]);
    *(f16x8*)&hj16[(size_t)n * 64 + c] = hq.v;
}

// ---------------- Kernel B: pairwise scores via fp16 MFMA ----------------
// 32x32 pair tile / block (4 waves). NO __syncthreads, no staging LDS:
// hi fragments are 16B broadcast loads from the L1/L2-hot hi16 table inside
// the loop; hj/w2 fragments live in registers. Loop: 2 global_load_dwordx4 ->
// 16 packed fp16 ops -> 4 MFMA (b2 as C operand) -> packed w3-dot -> one fp32
// LDS partial. Deferred wave-local epilogue, coalesced dwordx4 stores.
#define PSTR 68   // partial row stride (floats)

__global__ __launch_bounds__(256, 4) void pair_kernel(
    const float* __restrict__ ws,
    const float* __restrict__ w2, const float* __restrict__ b2,
    const float* __restrict__ w3, const float* __restrict__ b3,
    float* __restrict__ out)
{
    const int bx = blockIdx.x, by = blockIdx.y;
    const int i0 = by * 32, j0 = bx * 32;
    const int tid = threadIdx.x;

    if (bx < by) {   // entire tile strictly below diagonal -> zeros
        const float4 z = {0.f, 0.f, 0.f, 0.f};
        ((float4*)(out + (size_t)(i0 + (tid >> 3)) * NROWS + j0))[tid & 7] = z;
        return;
    }

    __shared__ float part[4 * 16 * PSTR];    // 17408 B, per-wave slices

    const _Float16* hi16 = (const _Float16*)(ws + H16_OFF);
    const _Float16* hj16 = hi16 + NROWS * 64;

    const int lane = tid & 63;
    const int wid  = tid >> 6;
    const int col  = lane & 15;
    const int quad = lane >> 4;
    const int wj   = wid & 1;
    const int wi   = wid >> 1;

    // hj fragments: lane's j = j0 + wj*16 + col, k = ks*32 + quad*8 + j
    const _Float16* hjr = hj16 + (size_t)(j0 + wj * 16 + col) * 64 + quad * 8;
    const f16x8 hj0 = *(const f16x8*)(hjr);
    const f16x8 hj1 = *(const f16x8*)(hjr + 32);

    // w2 A-frags (block-invariant): lane = channel ch*16+col, k = ks*32+quad*8+j
    H8 wf[2][2];
    #pragma unroll
    for (int ch = 0; ch < 2; ++ch)
        #pragma unroll
        for (int ks = 0; ks < 2; ++ks) {
            const f32x4* wr = (const f32x4*)(w2 + (ch * 16 + col) * 64 + ks * 32 + quad * 8);
            const f32x4 w0 = wr[0], w1v = wr[1];
            wf[ch][ks].h2[0] = pkrtz(w0[0], w0[1]);
            wf[ch][ks].h2[1] = pkrtz(w0[2], w0[3]);
            wf[ch][ks].h2[2] = pkrtz(w1v[0], w1v[1]);
            wf[ch][ks].h2[3] = pkrtz(w1v[2], w1v[3]);
        }
    // epilogue coefficients: lane's channels are quad*4+r (accA) / 16+quad*4+r (accB)
    const f32x4 b2A = *(const f32x4*)(b2 + quad * 4);
    const f32x4 b2B = *(const f32x4*)(b2 + 16 + quad * 4);
    const f32x4 w3A = *(const f32x4*)(w3 + quad * 4);
    const f32x4 w3B = *(const f32x4*)(w3 + 16 + quad * 4);
    const float b3v = b3[0];

    float* mypart = &part[wid * 16 * PSTR];
    const _Float16* hibase = hi16 + (size_t)(i0 + wi * 16) * 64 + quad * 8;

    #pragma unroll 8
    for (int it = 0; it < 16; ++it) {
        // hi broadcast loads: 16B, same addr across a quad's 16 lanes (L1-hot)
        const f16x8 x0 = *(const f16x8*)(hibase + it * 64);
        const f16x8 x1 = *(const f16x8*)(hibase + it * 64 + 32);

        // h = relu(hi + hj), all fp16 packed -> MFMA operand directly
        const f16x8 f0 = hmax0(x0 + hj0);
        const f16x8 f1 = hmax0(x1 + hj1);

        // b2 enters as the C operand of the first MFMA
        f32x4 accA = __builtin_amdgcn_mfma_f32_16x16x32_f16(wf[0][0].v, f0, b2A, 0, 0, 0);
        accA       = __builtin_amdgcn_mfma_f32_16x16x32_f16(wf[0][1].v, f1, accA, 0, 0, 0);
        f32x4 accB = __builtin_amdgcn_mfma_f32_16x16x32_f16(wf[1][0].v, f0, b2B, 0, 0, 0);
        accB       = __builtin_amdgcn_mfma_f32_16x16x32_f16(wf[1][1].v, f1, accB, 0, 0, 0);

        // relu + w3 partial dot over this lane's 8 channels; one fp32 LDS partial
        const f32x4 ra = vmax0(accA);
        const f32x4 rb = vmax0(accB);
        const f32x4 t4 = ra * w3A + rb * w3B;
        mypart[it * PSTR + quad * 16 + col] = (t4[0] + t4[1]) + (t4[2] + t4[3]);
    }

    // ---- deferred wave-local epilogue (same-wave producer: no barrier) ----
    {
        const int sub = lane & 3;            // j-col group (4 cols each)
        const int itx = lane >> 2;           // 0..15 -> i row
        const float* pr = &mypart[itx * PSTR + sub * 4];
        const f32x4 s = *(const f32x4*)(pr)
                      + *(const f32x4*)(pr + 16)
                      + *(const f32x4*)(pr + 32)
                      + *(const f32x4*)(pr + 48);
        const int i  = i0 + wi * 16 + itx;
        const int jb = j0 + wj * 16 + sub * 4;
        float4 o;
        o.x = (jb + 0 > i) ? 1.f / (1.f + __expf(-(s[0] + b3v))) : 0.f;
        o.y = (jb + 1 > i) ? 1.f / (1.f + __expf(-(s[1] + b3v))) : 0.f;
        o.z = (jb + 2 > i) ? 1.f / (1.f + __expf(-(s[2] + b3v))) : 0.f;
        o.w = (jb + 3 > i) ? 1.f / (1.f + __expf(-(s[3] + b3v))) : 0.f;
        *(float4*)(out + (size_t)i * NROWS + jb) = o;
    }
}

extern "C" void kernel_launch(void* const* d_in, const int* in_sizes, int n_in,
                              void* d_out, int out_size, void* d_ws, size_t ws_size,
                              hipStream_t stream) {
    const int*   subj_idx   = (const int*)d_in[0];
    const int*   rel_idx    = (const int*)d_in[1];
    const int*   obj_idx    = (const int*)d_in[2];
    const float* subj_table = (const float*)d_in[3];
    const float* rel_table  = (const float*)d_in[4];
    const float* obj_table  = (const float*)d_in[5];
    const float* proj_w     = (const float*)d_in[6];
    const float* proj_b     = (const float*)d_in[7];
    const float* w1         = (const float*)d_in[8];
    const float* b1         = (const float*)d_in[9];
    const float* w2         = (const float*)d_in[10];
    const float* b2         = (const float*)d_in[11];
    const float* w3         = (const float*)d_in[12];
    const float* b3         = (const float*)d_in[13];
    float* out = (float*)d_out;
    float* ws  = (float*)d_ws;

    tab_kernel<<<dim3(84), dim3(256), 0, stream>>>(
        subj_table, rel_table, obj_table, proj_w, proj_b, w1, b1, ws);

    hgather_kernel<<<dim3(NROWS / 32), dim3(256), 0, stream>>>(
        subj_idx, rel_idx, obj_idx, ws);

    pair_kernel<<<dim3(NROWS / 32, NROWS / 32), dim3(256), 0, stream>>>(
        ws, w2, b2, w3, b3, out);
}

// Round 11
// 111.560 us; speedup vs baseline: 1.1532x; 1.1532x over previous
//
#include <hip/hip_runtime.h>
#include <hip/hip_bf16.h>

#define NROWS 2048
#define HH 72    // LDS row stride in halves: 144 B, 16B-aligned

typedef __attribute__((ext_vector_type(4))) float f32x4;
typedef _Float16 f16x2 __attribute__((ext_vector_type(2)));
typedef _Float16 f16x8 __attribute__((ext_vector_type(8)));
typedef __fp16 fp16x2_raw __attribute__((ext_vector_type(2)));

union H8 { f16x8 v; f16x2 h2[4]; };

static __device__ __forceinline__ f32x4 vmax0(f32x4 a) {
    return __builtin_elementwise_max(a, (f32x4)0.f);
}
static __device__ __forceinline__ f16x8 hmax0(f16x8 a) {
    return __builtin_elementwise_max(a, (f16x8)(_Float16)0.f);
}
// v_cvt_pkrtz_f16_f32: returns __fp16x2; bit-cast to our _Float16x2
static __device__ __forceinline__ f16x2 pkrtz(float a, float b) {
    union { fp16x2_raw r; f16x2 f; } c;
    c.r = __builtin_amdgcn_cvt_pkrtz(a, b);
    return c.f;
}

// Workspace layout (float units):
//   TI   : ws[0    .. 2688)   42 x 64 (i-side: subj 0-15, rel 16-24, obj 25-40, const 41)
//   TJ   : ws[2688 .. 5376)   42 x 64 (j-side)
//   hi16 : ws[5376 .. )       2048 x 64 _Float16
//   hj16 : after hi16         2048 x 64 _Float16
#define TJ_OFF   2688
#define H16_OFF  5376

// ---------------- Kernel T: fused e-table + H-table ----------------
__global__ __launch_bounds__(256) void tab_kernel(
    const float* __restrict__ subj_table, const float* __restrict__ rel_table,
    const float* __restrict__ obj_table,
    const float* __restrict__ proj_w, const float* __restrict__ proj_b,
    const float* __restrict__ w1, const float* __restrict__ b1,
    float* __restrict__ ws)
{
    __shared__ float et[64];
    const int b = blockIdx.x;            // 0..83
    const int side = b & 1;
    const int r = b >> 1;                // 0..41
    const int tid = threadIdx.x;
    const int lane = tid & 63;
    const int w = tid >> 6;

    // ---- stage 1: ET row r ----
    if (r == 41) {
        if (tid < 64) et[tid] = proj_b[tid];
    } else {
        const float* src; int off;
        if (r < 16)      { src = subj_table + r * 64;        off = 0;   }
        else if (r < 25) { src = rel_table + (r - 16) * 64;  off = 64;  }
        else             { src = obj_table + (r - 25) * 64;  off = 128; }
        const float sv = src[lane];
        #pragma unroll
        for (int t = 0; t < 4; ++t) {
            const int d0 = w * 16 + t * 4;
            float p0 = sv * proj_w[(d0 + 0) * 192 + off + lane];
            float p1 = sv * proj_w[(d0 + 1) * 192 + off + lane];
            float p2 = sv * proj_w[(d0 + 2) * 192 + off + lane];
            float p3 = sv * proj_w[(d0 + 3) * 192 + off + lane];
            #pragma unroll
            for (int m = 1; m < 64; m <<= 1) {
                p0 += __shfl_xor(p0, m, 64);
                p1 += __shfl_xor(p1, m, 64);
                p2 += __shfl_xor(p2, m, 64);
                p3 += __shfl_xor(p3, m, 64);
            }
            if (lane == 0) {
                et[d0 + 0] = p0; et[d0 + 1] = p1;
                et[d0 + 2] = p2; et[d0 + 3] = p3;
            }
        }
    }
    __syncthreads();

    // ---- stage 2: H row ----
    float* dst = ws + (side ? TJ_OFF : 0);
    const float sv2 = et[lane];
    const int woff = side * 64;
    #pragma unroll
    for (int t = 0; t < 4; ++t) {
        const int d0 = w * 16 + t * 4;
        float p0 = sv2 * w1[(d0 + 0) * 128 + woff + lane];
        float p1 = sv2 * w1[(d0 + 1) * 128 + woff + lane];
        float p2 = sv2 * w1[(d0 + 2) * 128 + woff + lane];
        float p3 = sv2 * w1[(d0 + 3) * 128 + woff + lane];
        #pragma unroll
        for (int m = 1; m < 64; m <<= 1) {
            p0 += __shfl_xor(p0, m, 64);
            p1 += __shfl_xor(p1, m, 64);
            p2 += __shfl_xor(p2, m, 64);
            p3 += __shfl_xor(p3, m, 64);
        }
        if (lane == 0) {
            const bool cst = (side == 0) && (r == 41);
            dst[r * 64 + d0 + 0] = p0 + (cst ? b1[d0 + 0] : 0.f);
            dst[r * 64 + d0 + 1] = p1 + (cst ? b1[d0 + 1] : 0.f);
            dst[r * 64 + d0 + 2] = p2 + (cst ? b1[d0 + 2] : 0.f);
            dst[r * 64 + d0 + 3] = p3 + (cst ? b1[d0 + 3] : 0.f);
        }
    }
}

// ---------------- Kernel G: gather hi/hj rows -> fp16 tables ----------------
__global__ __launch_bounds__(256) void hgather_kernel(
    const int* __restrict__ subj_idx, const int* __restrict__ rel_idx,
    const int* __restrict__ obj_idx, float* __restrict__ ws)
{
    _Float16* hi16 = (_Float16*)(ws + H16_OFF);
    _Float16* hj16 = hi16 + NROWS * 64;
    const float* TI = ws;
    const float* TJ = ws + TJ_OFF;

    const int t = threadIdx.x;
    const int n = blockIdx.x * 32 + (t >> 3);
    const int c = (t & 7) * 8;

    const int s = subj_idx[n];
    const int r = 16 + rel_idx[n];
    const int o = 25 + obj_idx[n];

    const f32x4 v0 = *(const f32x4*)(TI + s * 64 + c)
                   + *(const f32x4*)(TI + r * 64 + c)
                   + *(const f32x4*)(TI + o * 64 + c)
                   + *(const f32x4*)(TI + 41 * 64 + c);
    const f32x4 v1 = *(const f32x4*)(TI + s * 64 + c + 4)
                   + *(const f32x4*)(TI + r * 64 + c + 4)
                   + *(const f32x4*)(TI + o * 64 + c + 4)
                   + *(const f32x4*)(TI + 41 * 64 + c + 4);
    H8 hp;
    hp.h2[0] = pkrtz(v0[0], v0[1]); hp.h2[1] = pkrtz(v0[2], v0[3]);
    hp.h2[2] = pkrtz(v1[0], v1[1]); hp.h2[3] = pkrtz(v1[2], v1[3]);
    *(f16x8*)&hi16[(size_t)n * 64 + c] = hp.v;

    const f32x4 u0 = *(const f32x4*)(TJ + s * 64 + c)
                   + *(const f32x4*)(TJ + r * 64 + c)
                   + *(const f32x4*)(TJ + o * 64 + c)
                   + *(const f32x4*)(TJ + 41 * 64 + c);
    const f32x4 u1 = *(const f32x4*)(TJ + s * 64 + c + 4)
                   + *(const f32x4*)(TJ + r * 64 + c + 4)
                   + *(const f32x4*)(TJ + o * 64 + c + 4)
                   + *(const f32x4*)(TJ + 41 * 64 + c + 4);
    H8 hq;
    hq.h2[0] = pkrtz(u0[0], u0[1]); hq.h2[1] = pkrtz(u0[2], u0[3]);
    hq.h2[2] = pkrtz(u1[0], u1[1]); hq.h2[3] = pkrtz(u1[2], u1[3]);
    *(f16x8*)&hj16[(size_t)n * 64 + c] = hq.v;
}

// ---------------- Kernel Z: lower-triangle zero fill ----------------
// 2016 blocks, bid -> (by,bx) with bx<by; each block zeroes one 32x32 tile.
__global__ __launch_bounds__(256) void zfill_kernel(float* __restrict__ out)
{
    const int bid = blockIdx.x;
    int by = (int)((1.f + sqrtf(1.f + 8.f * (float)bid)) * 0.5f);
    while (by * (by - 1) / 2 > bid) --by;
    while ((by + 1) * by / 2 <= bid) ++by;
    const int bx = bid - by * (by - 1) / 2;
    const int i0 = by * 32, j0 = bx * 32;
    const int t = threadIdx.x;
    const int r = t >> 3, c = (t & 7) * 4;
    const float4 z = {0.f, 0.f, 0.f, 0.f};
    *(float4*)(out + (size_t)(i0 + r) * NROWS + j0 + c) = z;
}

// ---------------- Kernel B: pairwise scores via fp16 MFMA ----------------
// Compact 1D triangular grid (2080 active blocks, bx>=by). Prologue: plain
// 16B copies of prebuilt fp16 h-rows global->LDS (no dependent gather chain).
// Inner loop (R8 structure): 2 ds_read_b128 -> packed fp16 add/max -> 4 MFMA
// (b2 as C operand) -> packed w3-dot -> one fp32 LDS partial. Deferred
// wave-local epilogue, coalesced dwordx4 stores.
#define PSTR 68   // partial row stride (floats)

__global__ __launch_bounds__(256, 4) void pair_kernel(
    const float* __restrict__ ws,
    const float* __restrict__ w2, const float* __restrict__ b2,
    const float* __restrict__ w3, const float* __restrict__ b3,
    float* __restrict__ out)
{
    const int bid = blockIdx.x;          // 0..2079, upper triangle incl diagonal
    int by = (int)((129.f - sqrtf(16641.f - 8.f * (float)bid)) * 0.5f);
    while (by * (129 - by) / 2 > bid) --by;
    while ((by + 1) * (129 - (by + 1)) / 2 <= bid) ++by;
    const int bx = by + (bid - by * (129 - by) / 2);
    const int i0 = by * 32, j0 = bx * 32;
    const int tid = threadIdx.x;

    __shared__ _Float16 hiL[32 * HH];        // 4608 B
    __shared__ _Float16 hjL[32 * HH];        // 4608 B
    __shared__ float part[4 * 16 * PSTR];    // 17408 B

    const _Float16* hi16 = (const _Float16*)(ws + H16_OFF);
    const _Float16* hj16 = hi16 + NROWS * 64;

    const int lane = tid & 63;
    const int wid  = tid >> 6;
    const int col  = lane & 15;
    const int quad = lane >> 4;
    const int wj   = wid & 1;
    const int wi   = wid >> 1;

    // ---- prologue: copy prebuilt fp16 rows -> LDS (single 16B load each) ----
    {
        const int rr = tid >> 3;             // 0..31
        const int cc = (tid & 7) * 8;        // halves
        *(f16x8*)&hiL[rr * HH + cc] = *(const f16x8*)(hi16 + (size_t)(i0 + rr) * 64 + cc);
        *(f16x8*)&hjL[rr * HH + cc] = *(const f16x8*)(hj16 + (size_t)(j0 + rr) * 64 + cc);
    }

    // w2 A-frags (block-invariant): lane = channel ch*16+col, k = ks*32+quad*8+j
    H8 wf[2][2];
    #pragma unroll
    for (int ch = 0; ch < 2; ++ch)
        #pragma unroll
        for (int ks = 0; ks < 2; ++ks) {
            const f32x4* wr = (const f32x4*)(w2 + (ch * 16 + col) * 64 + ks * 32 + quad * 8);
            const f32x4 w0 = wr[0], w1v = wr[1];
            wf[ch][ks].h2[0] = pkrtz(w0[0], w0[1]);
            wf[ch][ks].h2[1] = pkrtz(w0[2], w0[3]);
            wf[ch][ks].h2[2] = pkrtz(w1v[0], w1v[1]);
            wf[ch][ks].h2[3] = pkrtz(w1v[2], w1v[3]);
        }
    // epilogue coefficients: lane's channels are quad*4+r (accA) / 16+quad*4+r (accB)
    const f32x4 b2A = *(const f32x4*)(b2 + quad * 4);
    const f32x4 b2B = *(const f32x4*)(b2 + 16 + quad * 4);
    const f32x4 w3A = *(const f32x4*)(w3 + quad * 4);
    const f32x4 w3B = *(const f32x4*)(w3 + 16 + quad * 4);
    const float b3v = b3[0];

    __syncthreads();

    // loop-invariant hj fragments (this wave's 16 j's; lane's j = wj*16+col)
    const int hjb = (wj * 16 + col) * HH + quad * 8;
    const f16x8 hj0 = *(const f16x8*)&hjL[hjb];        // ks=0
    const f16x8 hj1 = *(const f16x8*)&hjL[hjb + 32];   // ks=1

    float* mypart = &part[wid * 16 * PSTR];

    #pragma unroll 8
    for (int it = 0; it < 16; ++it) {
        const int base = (wi * 16 + it) * HH + quad * 8;
        // hi broadcast reads (same addr across the 16 lanes of a quad)
        const f16x8 x0 = *(const f16x8*)&hiL[base];
        const f16x8 x1 = *(const f16x8*)&hiL[base + 32];

        // h = relu(hi + hj), all fp16 packed -> MFMA operand directly
        const f16x8 f0 = hmax0(x0 + hj0);
        const f16x8 f1 = hmax0(x1 + hj1);

        // b2 enters as the C operand of the first MFMA
        f32x4 accA = __builtin_amdgcn_mfma_f32_16x16x32_f16(wf[0][0].v, f0, b2A, 0, 0, 0);
        accA       = __builtin_amdgcn_mfma_f32_16x16x32_f16(wf[0][1].v, f1, accA, 0, 0, 0);
        f32x4 accB = __builtin_amdgcn_mfma_f32_16x16x32_f16(wf[1][0].v, f0, b2B, 0, 0, 0);
        accB       = __builtin_amdgcn_mfma_f32_16x16x32_f16(wf[1][1].v, f1, accB, 0, 0, 0);

        // relu + w3 partial dot over this lane's 8 channels; one fp32 LDS partial
        const f32x4 ra = vmax0(accA);
        const f32x4 rb = vmax0(accB);
        const f32x4 t4 = ra * w3A + rb * w3B;
        mypart[it * PSTR + quad * 16 + col] = (t4[0] + t4[1]) + (t4[2] + t4[3]);
    }

    // ---- deferred wave-local epilogue (same-wave producer: no barrier) ----
    {
        const int sub = lane & 3;            // j-col group (4 cols each)
        const int itx = lane >> 2;           // 0..15 -> i row
        const float* pr = &mypart[itx * PSTR + sub * 4];
        const f32x4 s = *(const f32x4*)(pr)
                      + *(const f32x4*)(pr + 16)
                      + *(const f32x4*)(pr + 32)
                      + *(const f32x4*)(pr + 48);
        const int i  = i0 + wi * 16 + itx;
        const int jb = j0 + wj * 16 + sub * 4;
        float4 o;
        o.x = (jb + 0 > i) ? 1.f / (1.f + __expf(-(s[0] + b3v))) : 0.f;
        o.y = (jb + 1 > i) ? 1.f / (1.f + __expf(-(s[1] + b3v))) : 0.f;
        o.z = (jb + 2 > i) ? 1.f / (1.f + __expf(-(s[2] + b3v))) : 0.f;
        o.w = (jb + 3 > i) ? 1.f / (1.f + __expf(-(s[3] + b3v))) : 0.f;
        *(float4*)(out + (size_t)i * NROWS + jb) = o;
    }
}

extern "C" void kernel_launch(void* const* d_in, const int* in_sizes, int n_in,
                              void* d_out, int out_size, void* d_ws, size_t ws_size,
                              hipStream_t stream) {
    const int*   subj_idx   = (const int*)d_in[0];
    const int*   rel_idx    = (const int*)d_in[1];
    const int*   obj_idx    = (const int*)d_in[2];
    const float* subj_table = (const float*)d_in[3];
    const float* rel_table  = (const float*)d_in[4];
    const float* obj_table  = (const float*)d_in[5];
    const float* proj_w     = (const float*)d_in[6];
    const float* proj_b     = (const float*)d_in[7];
    const float* w1         = (const float*)d_in[8];
    const float* b1         = (const float*)d_in[9];
    const float* w2         = (const float*)d_in[10];
    const float* b2         = (const float*)d_in[11];
    const float* w3         = (const float*)d_in[12];
    const float* b3         = (const float*)d_in[13];
    float* out = (float*)d_out;
    float* ws  = (float*)d_ws;

    zfill_kernel<<<dim3(2016), dim3(256), 0, stream>>>(out);

    tab_kernel<<<dim3(84), dim3(256), 0, stream>>>(
        subj_table, rel_table, obj_table, proj_w, proj_b, w1, b1, ws);

    hgather_kernel<<<dim3(NROWS / 32), dim3(256), 0, stream>>>(
        subj_idx, rel_idx, obj_idx, ws);

    pair_kernel<<<dim3(2080), dim3(256), 0, stream>>>(
        ws, w2, b2, w3, b3, out);
}